// Round 1
// baseline (468.306 us; speedup 1.0000x reference)
//
#include <hip/hip_runtime.h>

// CombineEmbeddings: out[b,s,:] = (idx[b,s] >= 0) ? patch[b, idx[b,s], :]
//                                                 : word[b, s, :]
// B=4, S=4096, P=2048, H=4096, fp32. Pure row-select copy — HBM-bound.
// One float4 per lane; row = t>>10 so the select branch is wave-uniform.

#define BB 4
#define SS 4096
#define PP 2048
#define HH 4096

__global__ __launch_bounds__(256) void CombineEmbeddings_50319836840460_kernel(
    const float4* __restrict__ word,    // [B, S, H/4]
    const float4* __restrict__ patch,   // [B, P, H/4]
    const int*    __restrict__ idx,     // [B, S]
    float4*       __restrict__ out)     // [B, S, H/4]
{
    const int Hv = HH / 4;  // 1024 float4 per row
    long long t = (long long)blockIdx.x * blockDim.x + threadIdx.x;
    int row = (int)(t >> 10);          // b*S + s   (Hv = 1024 = 2^10)
    int col = (int)(t & (Hv - 1));
    int b   = row >> 12;               // row / S   (S = 4096 = 2^12)

    int id = idx[row];                 // wave-uniform within a row
    float4 v;
    if (id >= 0) {
        v = patch[((long long)b * PP + id) * Hv + col];
    } else {
        v = word[t];                   // word layout == out layout
    }
    out[t] = v;
}

extern "C" void kernel_launch(void* const* d_in, const int* in_sizes, int n_in,
                              void* d_out, int out_size, void* d_ws, size_t ws_size,
                              hipStream_t stream) {
    const float4* word  = (const float4*)d_in[0];
    const float4* patch = (const float4*)d_in[1];
    const int*    idx   = (const int*)d_in[2];
    float4*       out   = (float4*)d_out;

    const long long total_vec = (long long)BB * SS * (HH / 4);  // 16,777,216
    const int block = 256;
    const int grid  = (int)(total_vec / block);                 // 65,536

    CombineEmbeddings_50319836840460_kernel<<<grid, block, 0, stream>>>(
        word, patch, idx, out);
}